// Round 6
// baseline (233.060 us; speedup 1.0000x reference)
//
#include <hip/hip_runtime.h>
#include <hip/hip_bf16.h>

#define IN_DIM    1024
#define HEAD_DIM  64
#define NUM_HEADS 16
#define SEQ       4096

// 1/sqrt(64) * log2(e), folded into Q (fp32, pre-bf16-cast). Softmax via exp2.
#define QSCALE 0.18033688011112042f

typedef __bf16 bf16;
typedef __attribute__((ext_vector_type(4))) __bf16 bf16x4;
typedef __attribute__((ext_vector_type(8))) __bf16 bf16x8;
typedef __attribute__((ext_vector_type(4))) float floatx4;

__device__ __forceinline__ void async16(bf16* lds, const bf16* g) {
    __builtin_amdgcn_global_load_lds(
        (const __attribute__((address_space(1))) unsigned int*)g,
        (__attribute__((address_space(3))) unsigned int*)lds, 16, 0, 0);
}

// ---------------------------------------------------------------------------
// ws layout: hb @0 (8MB) | Wt @8MB (6MB, n-major) | Qb @14MB | Kb @22MB | Vt @30MB
// ---------------------------------------------------------------------------

__global__ void mha_conv_h(const float* __restrict__ h, bf16* __restrict__ hb) {
    int i = blockIdx.x * blockDim.x + threadIdx.x;
    float4 v = ((const float4*)h)[i];
    bf16x4 r;
    r[0] = (bf16)v.x; r[1] = (bf16)v.y; r[2] = (bf16)v.z; r[3] = (bf16)v.w;
    ((bf16x4*)hb)[i] = r;
}

__global__ void mha_conv_wt(const float* __restrict__ Wq, const float* __restrict__ Wk,
                            const float* __restrict__ Wv, bf16* __restrict__ Wt) {
    __shared__ bf16 tile[64][65];
    const int mat = blockIdx.z;
    const float* W = (mat == 0) ? Wq : (mat == 1) ? Wk : Wv;
    const int k0 = blockIdx.y * 64, n0 = blockIdx.x * 64;
    const int tn = threadIdx.x & 63, tq = threadIdx.x >> 6;
#pragma unroll
    for (int i = 0; i < 16; ++i) {
        int kk = tq + i * 4;
        tile[kk][tn] = (bf16)W[(size_t)(k0 + kk) * 1024 + n0 + tn];
    }
    __syncthreads();
#pragma unroll
    for (int i = 0; i < 16; ++i) {
        int nn = tq + i * 4;
        Wt[((size_t)mat << 20) + (size_t)(n0 + nn) * 1024 + k0 + tn] = tile[tn][nn];
    }
}

// ---------------------------------------------------------------------------
// QKV GEMM, 128x128 tile, BK=32, global_load_lds staging, XOR swizzle.
// V block-columns (mat==2): MFMA operands swapped -> output is V^T directly
// (coalesced Vt stores). The swap branch is hoisted OUT of the K-loop.
// ---------------------------------------------------------------------------
__launch_bounds__(256)
__global__ void mha_qkv_gemm(const bf16* __restrict__ hb, const bf16* __restrict__ Wt,
                             const float* __restrict__ bq, const float* __restrict__ bk,
                             const float* __restrict__ bv,
                             bf16* __restrict__ Qb, bf16* __restrict__ Kb,
                             bf16* __restrict__ Vt) {
    __shared__ __align__(16) bf16 As[128 * 32];
    __shared__ __align__(16) bf16 Bs[128 * 32];

    const int lane = threadIdx.x & 63;
    const int wave = threadIdx.x >> 6;
    const int l16  = lane & 15;
    const int quad = lane >> 4;
    const int wm   = wave & 1;
    const int wn   = wave >> 1;

    const int m0  = blockIdx.x * 128;
    const int n0  = blockIdx.y * 128;
    const int mat = n0 >> 10;
    const int nc0 = n0 & 1023;

    const bf16* Wp = Wt + ((size_t)mat << 20);

    floatx4 acc[4][4] = {};
    const int swz = (l16 >> 1) & 3;

    // staging indices (shared by both loop variants)
    int g0 = wave * 128 + lane, g1 = g0 + 64;
    int row0 = g0 >> 2, gc0 = (g0 & 3) ^ ((row0 >> 1) & 3);
    int row1 = g1 >> 2, gc1 = (g1 & 3) ^ ((row1 >> 1) & 3);
    bf16* la0 = As + (size_t)(wave * 128) * 8;
    bf16* la1 = As + (size_t)(wave * 128 + 64) * 8;
    bf16* lb0 = Bs + (size_t)(wave * 128) * 8;
    bf16* lb1 = Bs + (size_t)(wave * 128 + 64) * 8;

    if (mat != 2) {
        for (int k0 = 0; k0 < IN_DIM; k0 += 32) {
            async16(la0, hb + (size_t)(m0 + row0) * IN_DIM + k0 + gc0 * 8);
            async16(la1, hb + (size_t)(m0 + row1) * IN_DIM + k0 + gc1 * 8);
            async16(lb0, Wp + (size_t)(nc0 + row0) * IN_DIM + k0 + gc0 * 8);
            async16(lb1, Wp + (size_t)(nc0 + row1) * IN_DIM + k0 + gc1 * 8);
            __syncthreads();
            bf16x8 af[4], bf[4];
#pragma unroll
            for (int mt = 0; mt < 4; ++mt)
                af[mt] = *(const bf16x8*)(As + (size_t)(wm * 64 + mt * 16 + l16) * 32
                                          + ((quad ^ swz) * 8));
#pragma unroll
            for (int nt = 0; nt < 4; ++nt)
                bf[nt] = *(const bf16x8*)(Bs + (size_t)(wn * 64 + nt * 16 + l16) * 32
                                          + ((quad ^ swz) * 8));
#pragma unroll
            for (int mt = 0; mt < 4; ++mt)
#pragma unroll
                for (int nt = 0; nt < 4; ++nt)
                    acc[mt][nt] = __builtin_amdgcn_mfma_f32_16x16x32_bf16(af[mt], bf[nt],
                                                                          acc[mt][nt], 0, 0, 0);
            __syncthreads();
        }
        const float* bias = (mat == 0) ? bq : bk;
#pragma unroll
        for (int nt = 0; nt < 4; ++nt) {
            int nc = nc0 + wn * 64 + nt * 16 + l16;
            float bb = bias[nc];
            int head = nc >> 6, d = nc & 63;
#pragma unroll
            for (int mt = 0; mt < 4; ++mt)
#pragma unroll
                for (int r = 0; r < 4; ++r) {
                    int srow = m0 + wm * 64 + mt * 16 + quad * 4 + r;
                    float v = acc[mt][nt][r] + bb;
                    if (mat == 0)
                        Qb[((size_t)head * SEQ + srow) * HEAD_DIM + d] = (bf16)(v * QSCALE);
                    else
                        Kb[((size_t)head * SEQ + srow) * HEAD_DIM + d] = (bf16)v;
                }
        }
    } else {
        for (int k0 = 0; k0 < IN_DIM; k0 += 32) {
            async16(la0, hb + (size_t)(m0 + row0) * IN_DIM + k0 + gc0 * 8);
            async16(la1, hb + (size_t)(m0 + row1) * IN_DIM + k0 + gc1 * 8);
            async16(lb0, Wp + (size_t)(nc0 + row0) * IN_DIM + k0 + gc0 * 8);
            async16(lb1, Wp + (size_t)(nc0 + row1) * IN_DIM + k0 + gc1 * 8);
            __syncthreads();
            bf16x8 af[4], bf[4];
#pragma unroll
            for (int mt = 0; mt < 4; ++mt)
                af[mt] = *(const bf16x8*)(As + (size_t)(wm * 64 + mt * 16 + l16) * 32
                                          + ((quad ^ swz) * 8));
#pragma unroll
            for (int nt = 0; nt < 4; ++nt)
                bf[nt] = *(const bf16x8*)(Bs + (size_t)(wn * 64 + nt * 16 + l16) * 32
                                          + ((quad ^ swz) * 8));
#pragma unroll
            for (int mt = 0; mt < 4; ++mt)
#pragma unroll
                for (int nt = 0; nt < 4; ++nt)
                    acc[mt][nt] = __builtin_amdgcn_mfma_f32_16x16x32_bf16(bf[nt], af[mt],
                                                                          acc[mt][nt], 0, 0, 0);
            __syncthreads();
        }
        // acc[mt][nt]: rows = n (d), cols = m (s)  -> coalesced V^T stores
#pragma unroll
        for (int nt = 0; nt < 4; ++nt)
#pragma unroll
            for (int r = 0; r < 4; ++r) {
                int n = nc0 + wn * 64 + nt * 16 + quad * 4 + r;
                float bb = bv[n];
                int head = n >> 6, d = n & 63;
#pragma unroll
                for (int mt = 0; mt < 4; ++mt) {
                    int s = m0 + wm * 64 + mt * 16 + l16;
                    Vt[((size_t)head * 64 + d) * SEQ + s] = (bf16)(acc[mt][nt][r] + bb);
                }
            }
    }
}

// ---------------------------------------------------------------------------
// Attention: 256 threads = 4 waves x 64 q-rows (4 m-tiles). K/V LDS tile reads
// amortized 4x vs R5 -> LDS pipe ~8.9 MB/CU (29 us floor) vs MFMA ~31 us.
// Same-interval S->PV per wave (per-wave P scratch, no S/PV barrier);
// K/V double-buffered via global_load_lds, 1 barrier/iter. exp2 softmax.
// ---------------------------------------------------------------------------
__launch_bounds__(256, 2)
__global__ void mha_attn(const bf16* __restrict__ Qb, const bf16* __restrict__ Kb,
                         const bf16* __restrict__ Vt, float* __restrict__ out) {
    __shared__ __align__(16) bf16 Ks[2][64 * 64];       // 16 KB
    __shared__ __align__(16) bf16 Vs[2][64 * 64];       // 16 KB
    __shared__ __align__(16) bf16 Ps[16][16 * 72];      // 36 KB  [wave*4+m]

    const int lane = threadIdx.x & 63;
    const int wave = threadIdx.x >> 6;
    const int l16  = lane & 15;
    const int quad = lane >> 4;

    const int hh    = blockIdx.y;
    const int qbase = blockIdx.x * 256 + wave * 64;

    const bf16* Qh = Qb + (size_t)hh * SEQ * HEAD_DIM;
    const bf16* Kh = Kb + (size_t)hh * SEQ * HEAD_DIM;
    const bf16* Vh = Vt + (size_t)hh * HEAD_DIM * SEQ;

    // staging: 512 16B-chunks per 64x64 tile; 256 threads stage 2 chunks each
    const int g0 = wave * 128 + lane, g1 = g0 + 64;
    const int sr0 = g0 >> 3, sc0 = (g0 & 7) ^ (sr0 & 7);
    const int sr1 = g1 >> 3, sc1 = (g1 & 7) ^ (sr1 & 7);

    bf16x8 qf[4][2];
#pragma unroll
    for (int m = 0; m < 4; ++m)
#pragma unroll
        for (int ks = 0; ks < 2; ++ks)
            qf[m][ks] = *(const bf16x8*)(Qh + (size_t)(qbase + m * 16 + l16) * HEAD_DIM
                                         + ks * 32 + quad * 8);

    bf16x8 vone;
#pragma unroll
    for (int i = 0; i < 8; ++i) vone[i] = (bf16)1.0f;

    floatx4 o[4][4] = {};
    floatx4 ol[4]   = {};

    const int swk = l16 & 7;

    auto stage = [&](int slot, int t) {
        async16(&Ks[slot][(wave * 128) * 8],      Kh + (size_t)(t * 64 + sr0) * HEAD_DIM + sc0 * 8);
        async16(&Ks[slot][(wave * 128 + 64) * 8], Kh + (size_t)(t * 64 + sr1) * HEAD_DIM + sc1 * 8);
        async16(&Vs[slot][(wave * 128) * 8],      Vh + (size_t)sr0 * SEQ + t * 64 + sc0 * 8);
        async16(&Vs[slot][(wave * 128 + 64) * 8], Vh + (size_t)sr1 * SEQ + t * 64 + sc1 * 8);
    };

    stage(0, 0);
    __syncthreads();

    for (int t = 0; t < 64; ++t) {
        const int cur = t & 1;
        if (t < 63) stage(cur ^ 1, t + 1);

        // ---- S^T = K Q^T ; exp2 ; pack -> per-wave P tiles ----------------
        bf16x8 kf[4][2];
#pragma unroll
        for (int tt = 0; tt < 4; ++tt)
#pragma unroll
            for (int ks = 0; ks < 2; ++ks)
                kf[tt][ks] = *(const bf16x8*)(&Ks[cur][(size_t)(tt * 16 + l16) * 64
                                              + (((ks * 4 + quad) ^ swk) * 8)]);
#pragma unroll
        for (int m = 0; m < 4; ++m) {
            bf16* lp = &Ps[wave * 4 + m][0];
#pragma unroll
            for (int tt = 0; tt < 4; ++tt) {
                floatx4 s = {};
                s = __builtin_amdgcn_mfma_f32_16x16x32_bf16(kf[tt][0], qf[m][0], s, 0, 0, 0);
                s = __builtin_amdgcn_mfma_f32_16x16x32_bf16(kf[tt][1], qf[m][1], s, 0, 0, 0);
                bf16x4 pk;
#pragma unroll
                for (int r = 0; r < 4; ++r) pk[r] = (bf16)__builtin_amdgcn_exp2f(s[r]);
                *(bf16x4*)(lp + l16 * 72 + tt * 16 + quad * 4) = pk;
            }
        }

        // ---- O += P V ; ol += P 1  (vf shared across all 4 m-tiles) -------
        bf16x8 vf[4][2];
#pragma unroll
        for (int dt = 0; dt < 4; ++dt)
#pragma unroll
            for (int ks = 0; ks < 2; ++ks)
                vf[dt][ks] = *(const bf16x8*)(&Vs[cur][(size_t)(dt * 16 + l16) * 64
                                              + (((ks * 4 + quad) ^ swk) * 8)]);
#pragma unroll
        for (int m = 0; m < 4; ++m) {
            bf16* lp = &Ps[wave * 4 + m][0];
#pragma unroll
            for (int ks = 0; ks < 2; ++ks) {
                bf16x8 pf = *(const bf16x8*)(lp + l16 * 72 + ks * 32 + quad * 8);
#pragma unroll
                for (int dt = 0; dt < 4; ++dt)
                    o[m][dt] = __builtin_amdgcn_mfma_f32_16x16x32_bf16(pf, vf[dt][ks],
                                                                       o[m][dt], 0, 0, 0);
                ol[m] = __builtin_amdgcn_mfma_f32_16x16x32_bf16(pf, vone, ol[m], 0, 0, 0);
            }
        }
        __syncthreads();   // K/V buffer handoff; drains prefetch issued at top
    }

#pragma unroll
    for (int m = 0; m < 4; ++m)
#pragma unroll
        for (int r = 0; r < 4; ++r) {
            float inv = 1.0f / ol[m][r];
            int srow_o = qbase + m * 16 + quad * 4 + r;
#pragma unroll
            for (int dt = 0; dt < 4; ++dt)
                out[(size_t)srow_o * (NUM_HEADS * HEAD_DIM) + hh * 64 + dt * 16 + l16]
                    = o[m][dt][r] * inv;
        }
}

extern "C" void kernel_launch(void* const* d_in, const int* in_sizes, int n_in,
                              void* d_out, int out_size, void* d_ws, size_t ws_size,
                              hipStream_t stream) {
    const float* h  = (const float*)d_in[0];
    const float* Wq = (const float*)d_in[1];
    const float* Wk = (const float*)d_in[2];
    const float* Wv = (const float*)d_in[3];
    const float* bq = (const float*)d_in[4];
    const float* bk = (const float*)d_in[5];
    const float* bv = (const float*)d_in[6];
    float* out = (float*)d_out;

    char* ws = (char*)d_ws;
    const size_t MB = 1024 * 1024;
    bf16* hb = (bf16*)(ws);
    bf16* Wt = (bf16*)(ws + 8 * MB);
    bf16* Qb = (bf16*)(ws + 14 * MB);
    bf16* Kb = (bf16*)(ws + 22 * MB);
    bf16* Vt = (bf16*)(ws + 30 * MB);

    mha_conv_h<<<(SEQ * IN_DIM / 4) / 256, 256, 0, stream>>>(h, hb);
    mha_conv_wt<<<dim3(16, 16, 3), 256, 0, stream>>>(Wq, Wk, Wv, Wt);
    mha_qkv_gemm<<<dim3(SEQ / 128, (3 * IN_DIM) / 128), 256, 0, stream>>>(
        hb, Wt, bq, bk, bv, Qb, Kb, Vt);
    mha_attn<<<dim3(SEQ / 256, NUM_HEADS), 256, 0, stream>>>(Qb, Kb, Vt, out);
}

// Round 7
// 212.531 us; speedup vs baseline: 1.0966x; 1.0966x over previous
//
#include <hip/hip_runtime.h>
#include <hip/hip_bf16.h>

#define IN_DIM    1024
#define HEAD_DIM  64
#define NUM_HEADS 16
#define SEQ       4096

// 1/sqrt(64) * log2(e), folded into Q (fp32, pre-bf16-cast). Softmax via exp2.
#define QSCALE 0.18033688011112042f

typedef __bf16 bf16;
typedef __attribute__((ext_vector_type(4))) __bf16 bf16x4;
typedef __attribute__((ext_vector_type(8))) __bf16 bf16x8;
typedef __attribute__((ext_vector_type(4))) float floatx4;

__device__ __forceinline__ void async16(bf16* lds, const bf16* g) {
    __builtin_amdgcn_global_load_lds(
        (const __attribute__((address_space(1))) unsigned int*)g,
        (__attribute__((address_space(3))) unsigned int*)lds, 16, 0, 0);
}

// ---------------------------------------------------------------------------
// ws layout (both modes): Qb@0 (8M) | Kb@8M | Vt@16M | hb@24M (8M) | Wt@32M (6M)
// split mode only (needs ~59.3 MB): Opart@24M (33.55M, overlays dead hb/Wt)
//                                   Lpart@57.6M (0.52M)
// ---------------------------------------------------------------------------

__global__ void mha_conv_h(const float* __restrict__ h, bf16* __restrict__ hb) {
    int i = blockIdx.x * blockDim.x + threadIdx.x;
    float4 v = ((const float4*)h)[i];
    bf16x4 r;
    r[0] = (bf16)v.x; r[1] = (bf16)v.y; r[2] = (bf16)v.z; r[3] = (bf16)v.w;
    ((bf16x4*)hb)[i] = r;
}

__global__ void mha_conv_wt(const float* __restrict__ Wq, const float* __restrict__ Wk,
                            const float* __restrict__ Wv, bf16* __restrict__ Wt) {
    __shared__ bf16 tile[64][65];
    const int mat = blockIdx.z;
    const float* W = (mat == 0) ? Wq : (mat == 1) ? Wk : Wv;
    const int k0 = blockIdx.y * 64, n0 = blockIdx.x * 64;
    const int tn = threadIdx.x & 63, tq = threadIdx.x >> 6;
#pragma unroll
    for (int i = 0; i < 16; ++i) {
        int kk = tq + i * 4;
        tile[kk][tn] = (bf16)W[(size_t)(k0 + kk) * 1024 + n0 + tn];
    }
    __syncthreads();
#pragma unroll
    for (int i = 0; i < 16; ++i) {
        int nn = tq + i * 4;
        Wt[((size_t)mat << 20) + (size_t)(n0 + nn) * 1024 + k0 + tn] = tile[tn][nn];
    }
}

// ---------------------------------------------------------------------------
// QKV GEMM: 128x128 tile, BK=32, global_load_lds staging, XOR swizzle.
// mat==2 (V): operands swapped -> V^T output, coalesced Vt stores.
// ---------------------------------------------------------------------------
__launch_bounds__(256)
__global__ void mha_qkv_gemm(const bf16* __restrict__ hb, const bf16* __restrict__ Wt,
                             const float* __restrict__ bq, const float* __restrict__ bk,
                             const float* __restrict__ bv,
                             bf16* __restrict__ Qb, bf16* __restrict__ Kb,
                             bf16* __restrict__ Vt) {
    __shared__ __align__(16) bf16 As[128 * 32];
    __shared__ __align__(16) bf16 Bs[128 * 32];

    const int lane = threadIdx.x & 63;
    const int wave = threadIdx.x >> 6;
    const int l16  = lane & 15;
    const int quad = lane >> 4;
    const int wm   = wave & 1;
    const int wn   = wave >> 1;

    const int m0  = blockIdx.x * 128;
    const int n0  = blockIdx.y * 128;
    const int mat = n0 >> 10;
    const int nc0 = n0 & 1023;

    const bf16* Wp = Wt + ((size_t)mat << 20);

    floatx4 acc[4][4] = {};
    const int swz = (l16 >> 1) & 3;

    int g0 = wave * 128 + lane, g1 = g0 + 64;
    int row0 = g0 >> 2, gc0 = (g0 & 3) ^ ((row0 >> 1) & 3);
    int row1 = g1 >> 2, gc1 = (g1 & 3) ^ ((row1 >> 1) & 3);
    bf16* la0 = As + (size_t)(wave * 128) * 8;
    bf16* la1 = As + (size_t)(wave * 128 + 64) * 8;
    bf16* lb0 = Bs + (size_t)(wave * 128) * 8;
    bf16* lb1 = Bs + (size_t)(wave * 128 + 64) * 8;

    if (mat != 2) {
        for (int k0 = 0; k0 < IN_DIM; k0 += 32) {
            async16(la0, hb + (size_t)(m0 + row0) * IN_DIM + k0 + gc0 * 8);
            async16(la1, hb + (size_t)(m0 + row1) * IN_DIM + k0 + gc1 * 8);
            async16(lb0, Wp + (size_t)(nc0 + row0) * IN_DIM + k0 + gc0 * 8);
            async16(lb1, Wp + (size_t)(nc0 + row1) * IN_DIM + k0 + gc1 * 8);
            __syncthreads();
            bf16x8 af[4], bf[4];
#pragma unroll
            for (int mt = 0; mt < 4; ++mt)
                af[mt] = *(const bf16x8*)(As + (size_t)(wm * 64 + mt * 16 + l16) * 32
                                          + ((quad ^ swz) * 8));
#pragma unroll
            for (int nt = 0; nt < 4; ++nt)
                bf[nt] = *(const bf16x8*)(Bs + (size_t)(wn * 64 + nt * 16 + l16) * 32
                                          + ((quad ^ swz) * 8));
#pragma unroll
            for (int mt = 0; mt < 4; ++mt)
#pragma unroll
                for (int nt = 0; nt < 4; ++nt)
                    acc[mt][nt] = __builtin_amdgcn_mfma_f32_16x16x32_bf16(af[mt], bf[nt],
                                                                          acc[mt][nt], 0, 0, 0);
            __syncthreads();
        }
        const float* bias = (mat == 0) ? bq : bk;
#pragma unroll
        for (int nt = 0; nt < 4; ++nt) {
            int nc = nc0 + wn * 64 + nt * 16 + l16;
            float bb = bias[nc];
            int head = nc >> 6, d = nc & 63;
#pragma unroll
            for (int mt = 0; mt < 4; ++mt)
#pragma unroll
                for (int r = 0; r < 4; ++r) {
                    int srow = m0 + wm * 64 + mt * 16 + quad * 4 + r;
                    float v = acc[mt][nt][r] + bb;
                    if (mat == 0)
                        Qb[((size_t)head * SEQ + srow) * HEAD_DIM + d] = (bf16)(v * QSCALE);
                    else
                        Kb[((size_t)head * SEQ + srow) * HEAD_DIM + d] = (bf16)v;
                }
        }
    } else {
        for (int k0 = 0; k0 < IN_DIM; k0 += 32) {
            async16(la0, hb + (size_t)(m0 + row0) * IN_DIM + k0 + gc0 * 8);
            async16(la1, hb + (size_t)(m0 + row1) * IN_DIM + k0 + gc1 * 8);
            async16(lb0, Wp + (size_t)(nc0 + row0) * IN_DIM + k0 + gc0 * 8);
            async16(lb1, Wp + (size_t)(nc0 + row1) * IN_DIM + k0 + gc1 * 8);
            __syncthreads();
            bf16x8 af[4], bf[4];
#pragma unroll
            for (int mt = 0; mt < 4; ++mt)
                af[mt] = *(const bf16x8*)(As + (size_t)(wm * 64 + mt * 16 + l16) * 32
                                          + ((quad ^ swz) * 8));
#pragma unroll
            for (int nt = 0; nt < 4; ++nt)
                bf[nt] = *(const bf16x8*)(Bs + (size_t)(wn * 64 + nt * 16 + l16) * 32
                                          + ((quad ^ swz) * 8));
#pragma unroll
            for (int mt = 0; mt < 4; ++mt)
#pragma unroll
                for (int nt = 0; nt < 4; ++nt)
                    acc[mt][nt] = __builtin_amdgcn_mfma_f32_16x16x32_bf16(bf[nt], af[mt],
                                                                          acc[mt][nt], 0, 0, 0);
            __syncthreads();
        }
#pragma unroll
        for (int nt = 0; nt < 4; ++nt)
#pragma unroll
            for (int r = 0; r < 4; ++r) {
                int n = nc0 + wn * 64 + nt * 16 + quad * 4 + r;
                float bb = bv[n];
                int head = n >> 6, d = n & 63;
#pragma unroll
                for (int mt = 0; mt < 4; ++mt) {
                    int s = m0 + wm * 64 + mt * 16 + l16;
                    Vt[((size_t)head * 64 + d) * SEQ + s] = (bf16)(acc[mt][nt][r] + bb);
                }
            }
    }
}

// ---------------------------------------------------------------------------
// Attention: 256 threads = 4 waves x 64 q-rows (4 m-tiles, K/V LDS reads
// amortized 4x). TS = t-split factor: grid.z blocks each cover SEQ/TS keys and
// write unnormalized fp32 partials (no-max softmax => partials sum linearly).
// TS=1 writes normalized output directly.
// ---------------------------------------------------------------------------
template<int TS>
__launch_bounds__(256, 2)
__global__ void mha_attn(const bf16* __restrict__ Qb, const bf16* __restrict__ Kb,
                         const bf16* __restrict__ Vt, float* __restrict__ Op,
                         float* __restrict__ Lp, float* __restrict__ out) {
    __shared__ __align__(16) bf16 Ks[2][64 * 64];
    __shared__ __align__(16) bf16 Vs[2][64 * 64];
    __shared__ __align__(16) bf16 Ps[16][16 * 72];

    const int lane = threadIdx.x & 63;
    const int wave = threadIdx.x >> 6;
    const int l16  = lane & 15;
    const int quad = lane >> 4;

    const int hh    = blockIdx.y;
    const int zz    = blockIdx.z;
    const int qbase = blockIdx.x * 256 + wave * 64;
    const int tbase = zz * (64 / TS);
    const int niter = 64 / TS;

    const bf16* Qh = Qb + (size_t)hh * SEQ * HEAD_DIM;
    const bf16* Kh = Kb + (size_t)hh * SEQ * HEAD_DIM;
    const bf16* Vh = Vt + (size_t)hh * HEAD_DIM * SEQ;

    const int g0 = wave * 128 + lane, g1 = g0 + 64;
    const int sr0 = g0 >> 3, sc0 = (g0 & 7) ^ (sr0 & 7);
    const int sr1 = g1 >> 3, sc1 = (g1 & 7) ^ (sr1 & 7);

    bf16x8 qf[4][2];
#pragma unroll
    for (int m = 0; m < 4; ++m)
#pragma unroll
        for (int ks = 0; ks < 2; ++ks)
            qf[m][ks] = *(const bf16x8*)(Qh + (size_t)(qbase + m * 16 + l16) * HEAD_DIM
                                         + ks * 32 + quad * 8);

    bf16x8 vone;
#pragma unroll
    for (int i = 0; i < 8; ++i) vone[i] = (bf16)1.0f;

    floatx4 o[4][4] = {};
    floatx4 ol[4]   = {};

    const int swk = l16 & 7;

    auto stage = [&](int slot, int t) {
        async16(&Ks[slot][(wave * 128) * 8],      Kh + (size_t)(t * 64 + sr0) * HEAD_DIM + sc0 * 8);
        async16(&Ks[slot][(wave * 128 + 64) * 8], Kh + (size_t)(t * 64 + sr1) * HEAD_DIM + sc1 * 8);
        async16(&Vs[slot][(wave * 128) * 8],      Vh + (size_t)sr0 * SEQ + t * 64 + sc0 * 8);
        async16(&Vs[slot][(wave * 128 + 64) * 8], Vh + (size_t)sr1 * SEQ + t * 64 + sc1 * 8);
    };

    stage(0, tbase);
    __syncthreads();

    for (int t = 0; t < niter; ++t) {
        const int cur = t & 1;
        if (t < niter - 1) stage(cur ^ 1, tbase + t + 1);

        bf16x8 kf[4][2];
#pragma unroll
        for (int tt = 0; tt < 4; ++tt)
#pragma unroll
            for (int ks = 0; ks < 2; ++ks)
                kf[tt][ks] = *(const bf16x8*)(&Ks[cur][(size_t)(tt * 16 + l16) * 64
                                              + (((ks * 4 + quad) ^ swk) * 8)]);
#pragma unroll
        for (int m = 0; m < 4; ++m) {
            bf16* lp = &Ps[wave * 4 + m][0];
#pragma unroll
            for (int tt = 0; tt < 4; ++tt) {
                floatx4 s = {};
                s = __builtin_amdgcn_mfma_f32_16x16x32_bf16(kf[tt][0], qf[m][0], s, 0, 0, 0);
                s = __builtin_amdgcn_mfma_f32_16x16x32_bf16(kf[tt][1], qf[m][1], s, 0, 0, 0);
                bf16x4 pk;
#pragma unroll
                for (int r = 0; r < 4; ++r) pk[r] = (bf16)__builtin_amdgcn_exp2f(s[r]);
                *(bf16x4*)(lp + l16 * 72 + tt * 16 + quad * 4) = pk;
            }
        }

        bf16x8 vf[4][2];
#pragma unroll
        for (int dt = 0; dt < 4; ++dt)
#pragma unroll
            for (int ks = 0; ks < 2; ++ks)
                vf[dt][ks] = *(const bf16x8*)(&Vs[cur][(size_t)(dt * 16 + l16) * 64
                                              + (((ks * 4 + quad) ^ swk) * 8)]);
#pragma unroll
        for (int m = 0; m < 4; ++m) {
            bf16* lp = &Ps[wave * 4 + m][0];
#pragma unroll
            for (int ks = 0; ks < 2; ++ks) {
                bf16x8 pf = *(const bf16x8*)(lp + l16 * 72 + ks * 32 + quad * 8);
#pragma unroll
                for (int dt = 0; dt < 4; ++dt)
                    o[m][dt] = __builtin_amdgcn_mfma_f32_16x16x32_bf16(pf, vf[dt][ks],
                                                                       o[m][dt], 0, 0, 0);
                ol[m] = __builtin_amdgcn_mfma_f32_16x16x32_bf16(pf, vone, ol[m], 0, 0, 0);
            }
        }
        __syncthreads();
    }

    if (TS == 1) {
#pragma unroll
        for (int m = 0; m < 4; ++m)
#pragma unroll
            for (int r = 0; r < 4; ++r) {
                float inv = 1.0f / ol[m][r];
                int srow = qbase + m * 16 + quad * 4 + r;
#pragma unroll
                for (int dt = 0; dt < 4; ++dt)
                    out[(size_t)srow * (NUM_HEADS * HEAD_DIM) + hh * 64 + dt * 16 + l16]
                        = o[m][dt][r] * inv;
            }
    } else {
        // unnormalized fp32 partials: Op[z][h][s][d], Lp[z][h][s]
        float* Oz = Op + ((size_t)(zz * NUM_HEADS + hh) * SEQ) * HEAD_DIM;
        float* Lz = Lp + (size_t)(zz * NUM_HEADS + hh) * SEQ;
#pragma unroll
        for (int m = 0; m < 4; ++m)
#pragma unroll
            for (int r = 0; r < 4; ++r) {
                int srow = qbase + m * 16 + quad * 4 + r;
#pragma unroll
                for (int dt = 0; dt < 4; ++dt)
                    Oz[(size_t)srow * HEAD_DIM + dt * 16 + l16] = o[m][dt][r];
                if (l16 == 0) Lz[srow] = ol[m][r];
            }
    }
}

// out[s][h*64+d] = (O0+O1) / (l0+l1)
__global__ void mha_combine(const float* __restrict__ Op, const float* __restrict__ Lp,
                            float* __restrict__ out) {
    int i = blockIdx.x * blockDim.x + threadIdx.x;    // 1M threads x float4
    int j = i * 4;
    int s = j >> 10, rem = j & 1023, hh = rem >> 6, d = rem & 63;
    size_t i0 = ((size_t)hh * SEQ + s) * HEAD_DIM + d;
    size_t i1 = ((size_t)(NUM_HEADS + hh) * SEQ + s) * HEAD_DIM + d;
    float4 a = *(const float4*)(Op + i0);
    float4 b = *(const float4*)(Op + i1);
    float l = Lp[(size_t)hh * SEQ + s] + Lp[(size_t)(NUM_HEADS + hh) * SEQ + s];
    float inv = 1.0f / l;
    float4 r;
    r.x = (a.x + b.x) * inv; r.y = (a.y + b.y) * inv;
    r.z = (a.z + b.z) * inv; r.w = (a.w + b.w) * inv;
    *(float4*)(out + j) = r;
}

extern "C" void kernel_launch(void* const* d_in, const int* in_sizes, int n_in,
                              void* d_out, int out_size, void* d_ws, size_t ws_size,
                              hipStream_t stream) {
    const float* h  = (const float*)d_in[0];
    const float* Wq = (const float*)d_in[1];
    const float* Wk = (const float*)d_in[2];
    const float* Wv = (const float*)d_in[3];
    const float* bq = (const float*)d_in[4];
    const float* bk = (const float*)d_in[5];
    const float* bv = (const float*)d_in[6];
    float* out = (float*)d_out;

    char* ws = (char*)d_ws;
    const size_t MB = 1024 * 1024;
    bf16* Qb = (bf16*)(ws);
    bf16* Kb = (bf16*)(ws + 8 * MB);
    bf16* Vt = (bf16*)(ws + 16 * MB);
    bf16* hb = (bf16*)(ws + 24 * MB);
    bf16* Wt = (bf16*)(ws + 32 * MB);
    float* Op = (float*)(ws + 24 * MB);                 // overlays hb/Wt (dead by then)
    float* Lp = (float*)(ws + 24 * MB + (size_t)2 * NUM_HEADS * SEQ * HEAD_DIM * 4);

    const size_t NEED = 24 * MB + (size_t)2 * NUM_HEADS * SEQ * HEAD_DIM * 4
                      + (size_t)2 * NUM_HEADS * SEQ * 4;
    const bool split = (ws_size >= NEED);

    mha_conv_h<<<(SEQ * IN_DIM / 4) / 256, 256, 0, stream>>>(h, hb);
    mha_conv_wt<<<dim3(16, 16, 3), 256, 0, stream>>>(Wq, Wk, Wv, Wt);
    mha_qkv_gemm<<<dim3(SEQ / 128, (3 * IN_DIM) / 128), 256, 0, stream>>>(
        hb, Wt, bq, bk, bv, Qb, Kb, Vt);
    if (split) {
        mha_attn<2><<<dim3(SEQ / 256, NUM_HEADS, 2), 256, 0, stream>>>(
            Qb, Kb, Vt, Op, Lp, out);
        mha_combine<<<(SEQ * IN_DIM / 4) / 256, 256, 0, stream>>>(Op, Lp, out);
    } else {
        mha_attn<1><<<dim3(SEQ / 256, NUM_HEADS, 1), 256, 0, stream>>>(
            Qb, Kb, Vt, Op, Lp, out);
    }
}